// Round 3
// baseline (250.797 us; speedup 1.0000x reference)
//
#include <hip/hip_runtime.h>

// ISTFT via batched real-IFFT (radix-4, in-place LDS) + in-LDS overlap-add.
//
// Identity: reference einsum with W_real/W_imag == win ⊙ IDFT_2048(hermitian
// extension); Im F[0], Im F[1024] multiply zero sin-columns (dropped).
// Per frame (n=2048, m=1024):
//   1) real-IFFT pack (k=0..1023), 1/m normalization folded in:
//      Z[k] = [ (X[k]+conj(X[m-k])) + i e^{+2πik/n}(X[k]-conj(X[m-k])) ]*0.5/m
//   2) 1024-pt complex inverse FFT: radix-4 DIT, base-4-digit-reversed input,
//      e^{+} twiddles, 5 stages, IN-PLACE LDS buffer (stages 0-3 wave-local).
//   3) x[2p]=Re z[p], x[2p+1]=Im z[p]; windowed samples accumulate into LDS OA.
//
// R11 vs R10 (counters: istft_oa 43 µs @ 16% HBM, 21% VALUBusy, 30% occupancy
// -> latency/occupancy-bound, not bytes): frames d and d+4 of a block have
// DISJOINT OA regions, so a 512-thread block runs them concurrently in two
// 4-wave halves (own FFT buffer each, shared OA window, no collisions).
// 4 pair-iterations instead of 8 serial frames: 2x waves in flight (8000),
// half the serial depth, 12 barriers instead of 24. LDS 39.9 KB -> 4
// blocks/CU = 32 waves/CU cap; __launch_bounds__(512,8) pins VGPR<=64 (same
// per-thread body compiled to exactly 64 in R10). Seam scheme unchanged.

#define N_FFT    2048
#define HOP      512
#define T_FRAMES 1000
#define F_BINS   1025
#define OUT_LEN  511488
#define FPB      8                         // frames per block
#define BPB      125                       // blocks per batch (125*8 = 1000)
#define OAF      5632                      // OA window floats: 8*512 + 1536

#define P(a) ((a) + ((a) >> 4))            // LDS pad (complex units)

__device__ __forceinline__ void cmul(float ar, float ai, float br, float bi,
                                     float& cr, float& ci) {
    cr = ar * br - ai * bi;
    ci = ar * bi + ai * br;
}

__global__ __launch_bounds__(512, 8) void istft_oa_kernel(const float* __restrict__ re,
                                                          const float* __restrict__ im,
                                                          const float* __restrict__ win,
                                                          float* __restrict__ scratch,
                                                          float* __restrict__ out) {
    __shared__ __align__(16) float2 buf[2176];     // two halves of P(1023)+2=1088
    __shared__ __align__(16) float2 oa2[OAF / 2];  // 2816 float2 = 5632 floats

    const int j   = blockIdx.x;            // block within batch
    const int b   = blockIdx.y;
    const int tid = threadIdx.x;
    const int h   = tid >> 8;              // half id: 0 -> frames d, 1 -> d+4
    const int lt  = tid & 255;             // lane within half
    const int t0  = j * FPB;
    float2* mybuf = buf + 1088 * h;

    // ---- zero the OA window (first OA add is 2 barriers away) ----
    {
        float4* z4 = (float4*)oa2;         // 1408 float4
        #pragma unroll
        for (int e = 0; e < 3; ++e) {
            int idx = tid + 512 * e;
            if (idx < 1408) z4[idx] = make_float4(0.f, 0.f, 0.f, 0.f);
        }
    }

    const float Sc = 0.5f / 1024.f;
    const float2* w2v = (const float2*)win;

    for (int d = 0; d < 4; ++d) {
        const int d_eff = d + 4 * h;
        const int f = b * T_FRAMES + t0 + d_eff;
        const float* fr = re + (size_t)f * F_BINS;
        const float* fi = im + (size_t)f * F_BINS;

        // ---- pack to Z, store base-4 digit-reversed ----
        #pragma unroll
        for (int k0 = 0; k0 < 1024; k0 += 256) {
            int k = k0 + lt;
            float ar = fr[k];
            float ai = (k == 0) ? 0.f : fi[k];          // Im F[0] dropped
            int mk = 1024 - k;
            float br = fr[mk];
            float bi = (mk == 1024) ? 0.f : fi[mk];     // Im F[1024] dropped
            float dr = ar - br, di = ai + bi;           // X[k] - conj(X[m-k])
            float ang = 3.14159265358979f * (float)k / 1024.f;
            float sn, cs;
            __sincosf(ang, &sn, &cs);
            float Zr = (ar + br - (cs * di + sn * dr)) * Sc;
            float Zi = (ai - bi + (cs * dr - sn * di)) * Sc;
            unsigned r10 = __brev((unsigned)k) >> 22;                       // 10b rev
            int rk = (int)(((r10 & 0x155u) << 1) | ((r10 >> 1) & 0x155u)); // digit-rev
            mybuf[P(rk)] = make_float2(Zr, Zi);
        }
        __syncthreads();   // digit-reversal scatter is cross-wave (within half)

        // ---- stage 0 (hm=1): twiddles == 1, in-place ----
        {
            int base = lt << 2;
            int i0 = P(base), i1 = P(base + 1), i2 = P(base + 2), i3 = P(base + 3);
            float2 a = mybuf[i0], bb = mybuf[i1], c = mybuf[i2], dd = mybuf[i3];
            float t0r = a.x + c.x,  t0i = a.y + c.y;
            float t1r = a.x - c.x,  t1i = a.y - c.y;
            float t2r = bb.x + dd.x, t2i = bb.y + dd.y;
            float t3r = bb.x - dd.x, t3i = bb.y - dd.y;
            mybuf[i0] = make_float2(t0r + t2r, t0i + t2i);
            mybuf[i1] = make_float2(t1r - t3i, t1i + t3r);   // + i*t3
            mybuf[i2] = make_float2(t0r - t2r, t0i - t2i);
            mybuf[i3] = make_float2(t1r + t3i, t1i - t3r);   // - i*t3
        }

        // ---- stages 1..3: wave-local (waves own disjoint 256-elem regions) ----
        #pragma unroll
        for (int s = 1; s < 4; ++s) {
            __builtin_amdgcn_wave_barrier();
            const int hm = 1 << (2 * s);
            const int jj   = lt & (hm - 1);
            const int base = ((lt - jj) << 2) + jj;
            float ang = 1.57079632679f * (float)jj / (float)hm;   // 2π j/(4hm)
            float s1, c1;
            __sincosf(ang, &s1, &c1);                  // w1 = e^{+i ang}
            float c2, s2, c3, s3;
            cmul(c1, s1, c1, s1, c2, s2);              // w2 = w1^2
            cmul(c2, s2, c1, s1, c3, s3);              // w3 = w1^3

            int i0 = P(base), i1 = P(base + hm), i2 = P(base + 2 * hm), i3 = P(base + 3 * hm);
            float2 a = mybuf[i0], bb = mybuf[i1], c = mybuf[i2], dd = mybuf[i3];
            float br_, bi_, cr_, ci_, dr_, di_;
            cmul(bb.x, bb.y, c1, s1, br_, bi_);
            cmul(c.x,  c.y,  c2, s2, cr_, ci_);
            cmul(dd.x, dd.y, c3, s3, dr_, di_);

            float t0r = a.x + cr_, t0i = a.y + ci_;
            float t1r = a.x - cr_, t1i = a.y - ci_;
            float t2r = br_ + dr_, t2i = bi_ + di_;
            float t3r = br_ - dr_, t3i = bi_ - di_;
            mybuf[i0] = make_float2(t0r + t2r, t0i + t2i);
            mybuf[i1] = make_float2(t1r - t3i, t1i + t3r);
            mybuf[i2] = make_float2(t0r - t2r, t0i - t2i);
            mybuf[i3] = make_float2(t1r + t3i, t1i - t3r);
        }
        __syncthreads();   // stage 4 spans all 1024 points: cross-wave (within half)

        // ---- stage 4 (hm=256) fused with window + OA accumulate ----
        {
            float ang = 1.57079632679f * (float)lt / 256.f;
            float s1, c1;
            __sincosf(ang, &s1, &c1);
            float c2, s2, c3, s3;
            cmul(c1, s1, c1, s1, c2, s2);
            cmul(c2, s2, c1, s1, c3, s3);

            int i0 = P(lt), i1 = P(lt + 256), i2 = P(lt + 512), i3 = P(lt + 768);
            float2 a = mybuf[i0], bb = mybuf[i1], c = mybuf[i2], dd = mybuf[i3];
            float br_, bi_, cr_, ci_, dr_, di_;
            cmul(bb.x, bb.y, c1, s1, br_, bi_);
            cmul(c.x,  c.y,  c2, s2, cr_, ci_);
            cmul(dd.x, dd.y, c3, s3, dr_, di_);

            float t0r = a.x + cr_, t0i = a.y + ci_;
            float t1r = a.x - cr_, t1i = a.y - ci_;
            float t2r = br_ + dr_, t2i = bi_ + di_;
            float t3r = br_ - dr_, t3i = bi_ - di_;

            float2 z0 = make_float2(t0r + t2r, t0i + t2i);
            float2 z1 = make_float2(t1r - t3i, t1i + t3r);
            float2 z2 = make_float2(t0r - t2r, t0i - t2i);
            float2 z3 = make_float2(t1r + t3i, t1i - t3r);

            float2 w0 = w2v[lt],       w1 = w2v[lt + 256];
            float2 w2 = w2v[lt + 512], w3 = w2v[lt + 768];

            const int base2 = 256 * d_eff;       // float2 index of 512*d_eff
            float2 v;
            v = oa2[base2 + lt];
            v.x += z0.x * w0.x;  v.y += z0.y * w0.y;
            oa2[base2 + lt] = v;
            v = oa2[base2 + lt + 256];
            v.x += z1.x * w1.x;  v.y += z1.y * w1.y;
            oa2[base2 + lt + 256] = v;
            v = oa2[base2 + lt + 512];
            v.x += z2.x * w2.x;  v.y += z2.y * w2.y;
            oa2[base2 + lt + 512] = v;
            v = oa2[base2 + lt + 768];
            v.x += z3.x * w3.x;  v.y += z3.y * w3.y;
            oa2[base2 + lt + 768] = v;
        }
        __syncthreads();   // order OA adds vs next pair; buf free for next pack
    }

    // ---- complete region: floats [1536, 4096) -> out, wss == 1.5 exact ----
    const float inv = 2.f / 3.f;
    const float4* oa4 = (const float4*)oa2;
    float4* o4 = (float4*)(out + (size_t)b * OUT_LEN + (size_t)4096 * j + 512);
    #pragma unroll
    for (int e = 0; e < 2; ++e) {                  // 640 float4
        int idx = tid + 512 * e;
        if (idx < 640) {
            float4 v = oa4[384 + idx];
            o4[idx] = make_float4(v.x * inv, v.y * inv, v.z * inv, v.w * inv);
        }
    }
    // ---- seams: lead floats [0,1536) , trail floats [4096,5632) -> scratch ----
    float4* sc4 = (float4*)(scratch + (((size_t)b * BPB + j) * 2) * 1536);
    #pragma unroll
    for (int e = 0; e < 2; ++e) {                  // 768 float4: 0..383 lead, 384..767 trail
        int idx = tid + 512 * e;
        if (idx < 768) {
            float4 v = (idx < 384) ? oa4[idx] : oa4[640 + idx];   // trail f4 base = 1024
            sc4[idx] = v;
        }
    }
}

// Seam g of batch b covers n in [4096g, 4096g+1536); sum the trailing partial
// of block g-1 and the leading partial of block g. wss == 1.5 for
// n in [1536, 512000); generic gather wss at the global edges.
__global__ __launch_bounds__(256) void seam_kernel(const float* __restrict__ scratch,
                                                   const float* __restrict__ win,
                                                   float* __restrict__ out) {
    const int g = blockIdx.x;                      // 0..125
    const int b = blockIdx.y;

    #pragma unroll
    for (int e = 0; e < 6; ++e) {                  // 1536 = 6*256
        int i = threadIdx.x + 256 * e;
        int n = 4096 * g + i;
        int m = n - 1024;
        if (m < 0 || m >= OUT_LEN) continue;
        float s = 0.f;
        if (g > 0)
            s += scratch[(((size_t)b * BPB + (g - 1)) * 2 + 1) * 1536 + i];
        if (g < BPB)
            s += scratch[(((size_t)b * BPB + g) * 2) * 1536 + i];
        float r;
        if (n >= 1536 && n < 512000) {
            r = s * (2.f / 3.f);
        } else {
            int thi = n >> 9; if (thi > T_FRAMES - 1) thi = T_FRAMES - 1;
            int tlo = (n - (N_FFT - HOP)) >> 9; if (tlo < 0) tlo = 0;
            float wss = 0.f;
            for (int t = tlo; t <= thi; ++t) {
                float w = win[n - (t << 9)];
                wss += w * w;
            }
            r = (wss > 1.17549435e-38f) ? s / wss : s;
        }
        out[(size_t)b * OUT_LEN + m] = r;
    }
}

extern "C" void kernel_launch(void* const* d_in, const int* in_sizes, int n_in,
                              void* d_out, int out_size, void* d_ws, size_t ws_size,
                              hipStream_t stream) {
    const float* re  = (const float*)d_in[0];
    const float* im  = (const float*)d_in[1];
    // d_in[2], d_in[3] (W_real, W_imag) unused: the FFT computes their action.
    const float* win = (const float*)d_in[4];
    float* out = (float*)d_out;

    float* scratch = (float*)d_ws;   // 8 * 125 * 2 * 1536 * 4 B = 12,288,000 B

    istft_oa_kernel<<<dim3(BPB, 8), 512, 0, stream>>>(re, im, win, scratch, out);
    seam_kernel<<<dim3(BPB + 1, 8), 256, 0, stream>>>(scratch, win, out);
}

// Round 9
// 151.966 us; speedup vs baseline: 1.6504x; 1.6504x over previous
//
#include <hip/hip_runtime.h>

// ISTFT via batched real-IFFT (radix-4, in-place LDS) + in-LDS overlap-add.
//
// Identity: reference einsum with W_real/W_imag == win ⊙ IDFT_2048(hermitian
// extension); Im F[0], Im F[1024] multiply zero sin-columns (dropped).
// Per frame (n=2048, m=1024):
//   1) real-IFFT pack (k=0..1023), 1/m normalization folded in:
//      Z[k] = [ (X[k]+conj(X[m-k])) + i e^{+2πik/n}(X[k]-conj(X[m-k])) ]*0.5/m
//   2) 1024-pt complex inverse FFT: radix-4 DIT, base-4-digit-reversed input,
//      e^{+} twiddles, 5 stages, IN-PLACE LDS buffer (stages 0-3 wave-local).
//   3) x[2p]=Re z[p], x[2p+1]=Im z[p]; windowed samples accumulate into LDS OA.
//
// R17 == R12 resubmitted (R13-R16 all hit infra failures; never run on HW).
// Memory-safety re-audit (R16): buf max idx P(1023)=1086<1088/half; oa2 max
// 2815<2816; out j=124 ends 510976<511488; scratch 3072 floats/block in
// 12.3 MB; fr[1024] max 8,198,999<8,200,000; all __syncthreads uniform.
// R12 vs R11 (counters: launch_bounds(512,8) forced VGPR=32 -> spills; FETCH
// 32->262 MB, WRITE 22->230 MB = ~440 MB spill traffic, VALUBusy 8.6%,
// 148 µs. The two-half structure DID raise occupancy 30->79%): keep R11's
// structure bit-for-bit, fix ONLY the bound -> __launch_bounds__(512, 4)
// (2 blocks/CU min -> VGPR cap 128; body needs ~64, no spill). Residency is
// then LDS-capped: 39.9 KB -> 4 blocks/CU = 32 waves/CU; grid gives 3.9.
//
// Structure (R11): frames d and d+4 of a block have DISJOINT OA regions, so a
// 512-thread block runs them concurrently in two 4-wave halves (own FFT
// buffer each, shared OA window, no collisions). 4 pair-iterations instead of
// 8 serial frames. Middle 2560 outputs/block complete in-block (wss == 1.5
// exact) -> stored directly; 1536-sample seams go to scratch as fp32
// partials; seam_kernel sums the two partials per boundary and normalizes.

#define N_FFT    2048
#define HOP      512
#define T_FRAMES 1000
#define F_BINS   1025
#define OUT_LEN  511488
#define FPB      8                         // frames per block
#define BPB      125                       // blocks per batch (125*8 = 1000)
#define OAF      5632                      // OA window floats: 8*512 + 1536

#define P(a) ((a) + ((a) >> 4))            // LDS pad (complex units)

__device__ __forceinline__ void cmul(float ar, float ai, float br, float bi,
                                     float& cr, float& ci) {
    cr = ar * br - ai * bi;
    ci = ar * bi + ai * br;
}

__global__ __launch_bounds__(512, 4) void istft_oa_kernel(const float* __restrict__ re,
                                                          const float* __restrict__ im,
                                                          const float* __restrict__ win,
                                                          float* __restrict__ scratch,
                                                          float* __restrict__ out) {
    __shared__ __align__(16) float2 buf[2176];     // two halves of P(1023)+2=1088
    __shared__ __align__(16) float2 oa2[OAF / 2];  // 2816 float2 = 5632 floats

    const int j   = blockIdx.x;            // block within batch
    const int b   = blockIdx.y;
    const int tid = threadIdx.x;
    const int h   = tid >> 8;              // half id: 0 -> frames d, 1 -> d+4
    const int lt  = tid & 255;             // lane within half
    const int t0  = j * FPB;
    float2* mybuf = buf + 1088 * h;

    // ---- zero the OA window (first OA add is 2 barriers away) ----
    {
        float4* z4 = (float4*)oa2;         // 1408 float4
        #pragma unroll
        for (int e = 0; e < 3; ++e) {
            int idx = tid + 512 * e;
            if (idx < 1408) z4[idx] = make_float4(0.f, 0.f, 0.f, 0.f);
        }
    }

    const float Sc = 0.5f / 1024.f;
    const float2* w2v = (const float2*)win;

    for (int d = 0; d < 4; ++d) {
        const int d_eff = d + 4 * h;
        const int f = b * T_FRAMES + t0 + d_eff;
        const float* fr = re + (size_t)f * F_BINS;
        const float* fi = im + (size_t)f * F_BINS;

        // ---- pack to Z, store base-4 digit-reversed ----
        #pragma unroll
        for (int k0 = 0; k0 < 1024; k0 += 256) {
            int k = k0 + lt;
            float ar = fr[k];
            float ai = (k == 0) ? 0.f : fi[k];          // Im F[0] dropped
            int mk = 1024 - k;
            float br = fr[mk];
            float bi = (mk == 1024) ? 0.f : fi[mk];     // Im F[1024] dropped
            float dr = ar - br, di = ai + bi;           // X[k] - conj(X[m-k])
            float ang = 3.14159265358979f * (float)k / 1024.f;
            float sn, cs;
            __sincosf(ang, &sn, &cs);
            float Zr = (ar + br - (cs * di + sn * dr)) * Sc;
            float Zi = (ai - bi + (cs * dr - sn * di)) * Sc;
            unsigned r10 = __brev((unsigned)k) >> 22;                       // 10b rev
            int rk = (int)(((r10 & 0x155u) << 1) | ((r10 >> 1) & 0x155u)); // digit-rev
            mybuf[P(rk)] = make_float2(Zr, Zi);
        }
        __syncthreads();   // digit-reversal scatter is cross-wave (within half)

        // ---- stage 0 (hm=1): twiddles == 1, in-place ----
        {
            int base = lt << 2;
            int i0 = P(base), i1 = P(base + 1), i2 = P(base + 2), i3 = P(base + 3);
            float2 a = mybuf[i0], bb = mybuf[i1], c = mybuf[i2], dd = mybuf[i3];
            float t0r = a.x + c.x,  t0i = a.y + c.y;
            float t1r = a.x - c.x,  t1i = a.y - c.y;
            float t2r = bb.x + dd.x, t2i = bb.y + dd.y;
            float t3r = bb.x - dd.x, t3i = bb.y - dd.y;
            mybuf[i0] = make_float2(t0r + t2r, t0i + t2i);
            mybuf[i1] = make_float2(t1r - t3i, t1i + t3r);   // + i*t3
            mybuf[i2] = make_float2(t0r - t2r, t0i - t2i);
            mybuf[i3] = make_float2(t1r + t3i, t1i - t3r);   // - i*t3
        }

        // ---- stages 1..3: wave-local (waves own disjoint 256-elem regions) ----
        #pragma unroll
        for (int s = 1; s < 4; ++s) {
            __builtin_amdgcn_wave_barrier();
            const int hm = 1 << (2 * s);
            const int jj   = lt & (hm - 1);
            const int base = ((lt - jj) << 2) + jj;
            float ang = 1.57079632679f * (float)jj / (float)hm;   // 2π j/(4hm)
            float s1, c1;
            __sincosf(ang, &s1, &c1);                  // w1 = e^{+i ang}
            float c2, s2, c3, s3;
            cmul(c1, s1, c1, s1, c2, s2);              // w2 = w1^2
            cmul(c2, s2, c1, s1, c3, s3);              // w3 = w1^3

            int i0 = P(base), i1 = P(base + hm), i2 = P(base + 2 * hm), i3 = P(base + 3 * hm);
            float2 a = mybuf[i0], bb = mybuf[i1], c = mybuf[i2], dd = mybuf[i3];
            float br_, bi_, cr_, ci_, dr_, di_;
            cmul(bb.x, bb.y, c1, s1, br_, bi_);
            cmul(c.x,  c.y,  c2, s2, cr_, ci_);
            cmul(dd.x, dd.y, c3, s3, dr_, di_);

            float t0r = a.x + cr_, t0i = a.y + ci_;
            float t1r = a.x - cr_, t1i = a.y - ci_;
            float t2r = br_ + dr_, t2i = bi_ + di_;
            float t3r = br_ - dr_, t3i = bi_ - di_;
            mybuf[i0] = make_float2(t0r + t2r, t0i + t2i);
            mybuf[i1] = make_float2(t1r - t3i, t1i + t3r);
            mybuf[i2] = make_float2(t0r - t2r, t0i - t2i);
            mybuf[i3] = make_float2(t1r + t3i, t1i - t3r);
        }
        __syncthreads();   // stage 4 spans all 1024 points: cross-wave (within half)

        // ---- stage 4 (hm=256) fused with window + OA accumulate ----
        {
            float ang = 1.57079632679f * (float)lt / 256.f;
            float s1, c1;
            __sincosf(ang, &s1, &c1);
            float c2, s2, c3, s3;
            cmul(c1, s1, c1, s1, c2, s2);
            cmul(c2, s2, c1, s1, c3, s3);

            int i0 = P(lt), i1 = P(lt + 256), i2 = P(lt + 512), i3 = P(lt + 768);
            float2 a = mybuf[i0], bb = mybuf[i1], c = mybuf[i2], dd = mybuf[i3];
            float br_, bi_, cr_, ci_, dr_, di_;
            cmul(bb.x, bb.y, c1, s1, br_, bi_);
            cmul(c.x,  c.y,  c2, s2, cr_, ci_);
            cmul(dd.x, dd.y, c3, s3, dr_, di_);

            float t0r = a.x + cr_, t0i = a.y + ci_;
            float t1r = a.x - cr_, t1i = a.y - ci_;
            float t2r = br_ + dr_, t2i = bi_ + di_;
            float t3r = br_ - dr_, t3i = bi_ - di_;

            float2 z0 = make_float2(t0r + t2r, t0i + t2i);
            float2 z1 = make_float2(t1r - t3i, t1i + t3r);
            float2 z2 = make_float2(t0r - t2r, t0i - t2i);
            float2 z3 = make_float2(t1r + t3i, t1i - t3r);

            float2 w0 = w2v[lt],       w1 = w2v[lt + 256];
            float2 w2 = w2v[lt + 512], w3 = w2v[lt + 768];

            const int base2 = 256 * d_eff;       // float2 index of 512*d_eff
            float2 v;
            v = oa2[base2 + lt];
            v.x += z0.x * w0.x;  v.y += z0.y * w0.y;
            oa2[base2 + lt] = v;
            v = oa2[base2 + lt + 256];
            v.x += z1.x * w1.x;  v.y += z1.y * w1.y;
            oa2[base2 + lt + 256] = v;
            v = oa2[base2 + lt + 512];
            v.x += z2.x * w2.x;  v.y += z2.y * w2.y;
            oa2[base2 + lt + 512] = v;
            v = oa2[base2 + lt + 768];
            v.x += z3.x * w3.x;  v.y += z3.y * w3.y;
            oa2[base2 + lt + 768] = v;
        }
        __syncthreads();   // order OA adds vs next pair; buf free for next pack
    }

    // ---- complete region: floats [1536, 4096) -> out, wss == 1.5 exact ----
    const float inv = 2.f / 3.f;
    const float4* oa4 = (const float4*)oa2;
    float4* o4 = (float4*)(out + (size_t)b * OUT_LEN + (size_t)4096 * j + 512);
    #pragma unroll
    for (int e = 0; e < 2; ++e) {                  // 640 float4
        int idx = tid + 512 * e;
        if (idx < 640) {
            float4 v = oa4[384 + idx];
            o4[idx] = make_float4(v.x * inv, v.y * inv, v.z * inv, v.w * inv);
        }
    }
    // ---- seams: lead floats [0,1536) , trail floats [4096,5632) -> scratch ----
    float4* sc4 = (float4*)(scratch + (((size_t)b * BPB + j) * 2) * 1536);
    #pragma unroll
    for (int e = 0; e < 2; ++e) {                  // 768 float4: 0..383 lead, 384..767 trail
        int idx = tid + 512 * e;
        if (idx < 768) {
            float4 v = (idx < 384) ? oa4[idx] : oa4[640 + idx];   // trail f4 base = 1024
            sc4[idx] = v;
        }
    }
}

// Seam g of batch b covers n in [4096g, 4096g+1536); sum the trailing partial
// of block g-1 and the leading partial of block g. wss == 1.5 for
// n in [1536, 512000); generic gather wss at the global edges.
__global__ __launch_bounds__(256) void seam_kernel(const float* __restrict__ scratch,
                                                   const float* __restrict__ win,
                                                   float* __restrict__ out) {
    const int g = blockIdx.x;                      // 0..125
    const int b = blockIdx.y;

    #pragma unroll
    for (int e = 0; e < 6; ++e) {                  // 1536 = 6*256
        int i = threadIdx.x + 256 * e;
        int n = 4096 * g + i;
        int m = n - 1024;
        if (m < 0 || m >= OUT_LEN) continue;
        float s = 0.f;
        if (g > 0)
            s += scratch[(((size_t)b * BPB + (g - 1)) * 2 + 1) * 1536 + i];
        if (g < BPB)
            s += scratch[(((size_t)b * BPB + g) * 2) * 1536 + i];
        float r;
        if (n >= 1536 && n < 512000) {
            r = s * (2.f / 3.f);
        } else {
            int thi = n >> 9; if (thi > T_FRAMES - 1) thi = T_FRAMES - 1;
            int tlo = (n - (N_FFT - HOP)) >> 9; if (tlo < 0) tlo = 0;
            float wss = 0.f;
            for (int t = tlo; t <= thi; ++t) {
                float w = win[n - (t << 9)];
                wss += w * w;
            }
            r = (wss > 1.17549435e-38f) ? s / wss : s;
        }
        out[(size_t)b * OUT_LEN + m] = r;
    }
}

extern "C" void kernel_launch(void* const* d_in, const int* in_sizes, int n_in,
                              void* d_out, int out_size, void* d_ws, size_t ws_size,
                              hipStream_t stream) {
    const float* re  = (const float*)d_in[0];
    const float* im  = (const float*)d_in[1];
    // d_in[2], d_in[3] (W_real, W_imag) unused: the FFT computes their action.
    const float* win = (const float*)d_in[4];
    float* out = (float*)d_out;

    float* scratch = (float*)d_ws;   // 8 * 125 * 2 * 1536 * 4 B = 12,288,000 B

    istft_oa_kernel<<<dim3(BPB, 8), 512, 0, stream>>>(re, im, win, scratch, out);
    seam_kernel<<<dim3(BPB + 1, 8), 256, 0, stream>>>(scratch, win, out);
}

// Round 10
// 145.083 us; speedup vs baseline: 1.7286x; 1.0474x over previous
//
#include <hip/hip_runtime.h>

// ISTFT via batched real-IFFT (radix-4, in-place LDS) + in-LDS overlap-add.
//
// Identity: reference einsum with W_real/W_imag == win ⊙ IDFT_2048(hermitian
// extension); Im F[0], Im F[1024] multiply zero sin-columns (dropped).
// Per frame (n=2048, m=1024):
//   1) real-IFFT pack (k=0..1023), 1/m normalization folded in:
//      Z[k] = [ (X[k]+conj(X[m-k])) + i e^{+2πik/n}(X[k]-conj(X[m-k])) ]*0.5/m
//   2) 1024-pt complex inverse FFT: radix-4 DIT, base-4-digit-reversed input,
//      e^{+} twiddles, 5 stages, IN-PLACE LDS buffer (stages 0-3 wave-local).
//   3) x[2p]=Re z[p], x[2p+1]=Im z[p]; windowed samples accumulate into LDS OA.
//
// R18 vs R12 (measured: spills fixed exactly as predicted — VGPR 64, FETCH
// 34 MB, WRITE 29.5 MB — but dur 46.5 µs ~= R10's 43: Occupancy STUCK at 32%
// (~10 waves/CU, ~1.3 blocks/CU resident). 1000 heavyweight blocks never fill
// the machine; the grid is too coarse):
//  - FPB 8->4, 256-thread blocks -> 2000 blocks, 4 serial frames each
//    (2x parallelism, half the depth). LDS 23 KB -> 7 blocks/CU cap.
//  - Twiddles HOISTED out of the d-loop (pack phases + stage 1..4 triples are
//    frame-independent): ~32 regs, deletes 8 __sincosf + 8 cmul per
//    iteration (~35% of per-iter VALU). VGPR ~100 < 128 cap of (256,4).
//  - Seam pitch 2048 (g=0..250), scratch 24.6 MB; direct-out 512/block.
//
// Structure: middle 512 outputs/block complete in-block (wss == 1.5 exact)
// -> stored directly; 1536-sample seams stored as fp32 partials; seam_kernel
// sums trail(g-1)+lead(g) and normalizes (generic wss only at global edges).

#define N_FFT    2048
#define HOP      512
#define T_FRAMES 1000
#define F_BINS   1025
#define OUT_LEN  511488
#define FPB      4                         // frames per block
#define BPB      250                       // blocks per batch (250*4 = 1000)
#define OAF      3584                      // OA window floats: 4*512 + 1536

#define P(a) ((a) + ((a) >> 4))            // LDS pad (complex units)

__device__ __forceinline__ void cmul(float ar, float ai, float br, float bi,
                                     float& cr, float& ci) {
    cr = ar * br - ai * bi;
    ci = ar * bi + ai * br;
}

__global__ __launch_bounds__(256, 4) void istft_oa_kernel(const float* __restrict__ re,
                                                          const float* __restrict__ im,
                                                          const float* __restrict__ win,
                                                          float* __restrict__ scratch,
                                                          float* __restrict__ out) {
    __shared__ __align__(16) float2 buf[1088];     // P(1023)=1086
    __shared__ __align__(16) float2 oa2[OAF / 2];  // 1792 float2 = 3584 floats

    const int j   = blockIdx.x;            // block within batch
    const int b   = blockIdx.y;
    const int tid = threadIdx.x;
    const int t0  = j * FPB;

    // ---- zero the OA window (896 float4) ----
    {
        float4* z4 = (float4*)oa2;
        #pragma unroll
        for (int e = 0; e < 4; ++e) {
            int idx = tid + 256 * e;
            if (idx < 896) z4[idx] = make_float4(0.f, 0.f, 0.f, 0.f);
        }
    }

    // ---- hoisted twiddles (identical for all FPB frames) ----
    float pcs[4], psn[4];                  // pack: e^{i pi k/1024}, k = tid+256q
    #pragma unroll
    for (int q = 0; q < 4; ++q) {
        float ang = 3.14159265358979f * (float)(tid + 256 * q) / 1024.f;
        __sincosf(ang, &psn[q], &pcs[q]);
    }
    float tc1[4], ts1[4], tc2[4], ts2[4], tc3[4], ts3[4];  // [0..2]=stages1..3, [3]=stage4
    #pragma unroll
    for (int s = 1; s < 4; ++s) {
        const int hm = 1 << (2 * s);
        const int jj = tid & (hm - 1);
        float ang = 1.57079632679f * (float)jj / (float)hm;   // 2π j/(4hm)
        __sincosf(ang, &ts1[s - 1], &tc1[s - 1]);
        cmul(tc1[s-1], ts1[s-1], tc1[s-1], ts1[s-1], tc2[s-1], ts2[s-1]);
        cmul(tc2[s-1], ts2[s-1], tc1[s-1], ts1[s-1], tc3[s-1], ts3[s-1]);
    }
    {
        float ang = 1.57079632679f * (float)tid / 256.f;      // stage 4 (hm=256)
        __sincosf(ang, &ts1[3], &tc1[3]);
        cmul(tc1[3], ts1[3], tc1[3], ts1[3], tc2[3], ts2[3]);
        cmul(tc2[3], ts2[3], tc1[3], ts1[3], tc3[3], ts3[3]);
    }

    const float Sc = 0.5f / 1024.f;
    const float2* w2v = (const float2*)win;

    for (int d = 0; d < FPB; ++d) {
        const int f = b * T_FRAMES + t0 + d;
        const float* fr = re + (size_t)f * F_BINS;
        const float* fi = im + (size_t)f * F_BINS;

        // ---- pack to Z, store base-4 digit-reversed ----
        #pragma unroll
        for (int q = 0; q < 4; ++q) {
            int k = 256 * q + tid;
            float ar = fr[k];
            float ai = (k == 0) ? 0.f : fi[k];          // Im F[0] dropped
            int mk = 1024 - k;
            float br = fr[mk];
            float bi = (mk == 1024) ? 0.f : fi[mk];     // Im F[1024] dropped
            float dr = ar - br, di = ai + bi;           // X[k] - conj(X[m-k])
            float cs = pcs[q], sn = psn[q];
            float Zr = (ar + br - (cs * di + sn * dr)) * Sc;
            float Zi = (ai - bi + (cs * dr - sn * di)) * Sc;
            unsigned r10 = __brev((unsigned)k) >> 22;                       // 10b rev
            int rk = (int)(((r10 & 0x155u) << 1) | ((r10 >> 1) & 0x155u)); // digit-rev
            buf[P(rk)] = make_float2(Zr, Zi);
        }
        __syncthreads();   // digit-reversal scatter is cross-wave

        // ---- stage 0 (hm=1): twiddles == 1, in-place ----
        {
            int base = tid << 2;
            int i0 = P(base), i1 = P(base + 1), i2 = P(base + 2), i3 = P(base + 3);
            float2 a = buf[i0], bb = buf[i1], c = buf[i2], dd = buf[i3];
            float t0r = a.x + c.x,  t0i = a.y + c.y;
            float t1r = a.x - c.x,  t1i = a.y - c.y;
            float t2r = bb.x + dd.x, t2i = bb.y + dd.y;
            float t3r = bb.x - dd.x, t3i = bb.y - dd.y;
            buf[i0] = make_float2(t0r + t2r, t0i + t2i);
            buf[i1] = make_float2(t1r - t3i, t1i + t3r);   // + i*t3
            buf[i2] = make_float2(t0r - t2r, t0i - t2i);
            buf[i3] = make_float2(t1r + t3i, t1i - t3r);   // - i*t3
        }

        // ---- stages 1..3: wave-local (waves own disjoint 256-elem regions) ----
        #pragma unroll
        for (int s = 1; s < 4; ++s) {
            __builtin_amdgcn_wave_barrier();
            const int hm = 1 << (2 * s);
            const int jj   = tid & (hm - 1);
            const int base = ((tid - jj) << 2) + jj;
            const float c1 = tc1[s-1], s1v = ts1[s-1];
            const float c2 = tc2[s-1], s2v = ts2[s-1];
            const float c3 = tc3[s-1], s3v = ts3[s-1];

            int i0 = P(base), i1 = P(base + hm), i2 = P(base + 2 * hm), i3 = P(base + 3 * hm);
            float2 a = buf[i0], bb = buf[i1], c = buf[i2], dd = buf[i3];
            float br_, bi_, cr_, ci_, dr_, di_;
            cmul(bb.x, bb.y, c1, s1v, br_, bi_);
            cmul(c.x,  c.y,  c2, s2v, cr_, ci_);
            cmul(dd.x, dd.y, c3, s3v, dr_, di_);

            float t0r = a.x + cr_, t0i = a.y + ci_;
            float t1r = a.x - cr_, t1i = a.y - ci_;
            float t2r = br_ + dr_, t2i = bi_ + di_;
            float t3r = br_ - dr_, t3i = bi_ - di_;
            buf[i0] = make_float2(t0r + t2r, t0i + t2i);
            buf[i1] = make_float2(t1r - t3i, t1i + t3r);
            buf[i2] = make_float2(t0r - t2r, t0i - t2i);
            buf[i3] = make_float2(t1r + t3i, t1i - t3r);
        }
        __syncthreads();   // stage 4 spans all 1024 points: cross-wave

        // ---- stage 4 (hm=256) fused with window + OA accumulate ----
        {
            const float c1 = tc1[3], s1v = ts1[3];
            const float c2 = tc2[3], s2v = ts2[3];
            const float c3 = tc3[3], s3v = ts3[3];

            int i0 = P(tid), i1 = P(tid + 256), i2 = P(tid + 512), i3 = P(tid + 768);
            float2 a = buf[i0], bb = buf[i1], c = buf[i2], dd = buf[i3];
            float br_, bi_, cr_, ci_, dr_, di_;
            cmul(bb.x, bb.y, c1, s1v, br_, bi_);
            cmul(c.x,  c.y,  c2, s2v, cr_, ci_);
            cmul(dd.x, dd.y, c3, s3v, dr_, di_);

            float t0r = a.x + cr_, t0i = a.y + ci_;
            float t1r = a.x - cr_, t1i = a.y - ci_;
            float t2r = br_ + dr_, t2i = bi_ + di_;
            float t3r = br_ - dr_, t3i = bi_ - di_;

            float2 z0 = make_float2(t0r + t2r, t0i + t2i);
            float2 z1 = make_float2(t1r - t3i, t1i + t3r);
            float2 z2 = make_float2(t0r - t2r, t0i - t2i);
            float2 z3 = make_float2(t1r + t3i, t1i - t3r);

            float2 w0 = w2v[tid],       w1 = w2v[tid + 256];
            float2 w2 = w2v[tid + 512], w3 = w2v[tid + 768];

            const int base2 = 256 * d;           // float2 index of 512*d
            float2 v;
            v = oa2[base2 + tid];
            v.x += z0.x * w0.x;  v.y += z0.y * w0.y;
            oa2[base2 + tid] = v;
            v = oa2[base2 + tid + 256];
            v.x += z1.x * w1.x;  v.y += z1.y * w1.y;
            oa2[base2 + tid + 256] = v;
            v = oa2[base2 + tid + 512];
            v.x += z2.x * w2.x;  v.y += z2.y * w2.y;
            oa2[base2 + tid + 512] = v;
            v = oa2[base2 + tid + 768];
            v.x += z3.x * w3.x;  v.y += z3.y * w3.y;
            oa2[base2 + tid + 768] = v;
        }
        __syncthreads();   // order OA adds vs next frame; buf free for next pack
    }

    // ---- complete region: floats [1536, 2048) -> out, wss == 1.5 exact ----
    const float inv = 2.f / 3.f;
    const float4* oa4 = (const float4*)oa2;
    if (tid < 128) {                              // 128 float4 = 512 floats
        float4 v = oa4[384 + tid];
        float4* o4 = (float4*)(out + (size_t)b * OUT_LEN + (size_t)2048 * j + 512);
        o4[tid] = make_float4(v.x * inv, v.y * inv, v.z * inv, v.w * inv);
    }
    // ---- seams: lead floats [0,1536), trail floats [2048,3584) -> scratch ----
    float4* sc4 = (float4*)(scratch + (((size_t)b * BPB + j) * 2) * 1536);
    #pragma unroll
    for (int e = 0; e < 3; ++e) {                 // 768 float4 exactly
        int idx = tid + 256 * e;
        float4 v = (idx < 384) ? oa4[idx] : oa4[idx + 128];  // trail f4 base = 512
        sc4[idx] = v;
    }
}

// Seam g of batch b covers n in [2048g, 2048g+1536); sum the trailing partial
// of block g-1 and the leading partial of block g. wss == 1.5 for
// n in [1536, 512000); generic gather wss at the global edges.
__global__ __launch_bounds__(256) void seam_kernel(const float* __restrict__ scratch,
                                                   const float* __restrict__ win,
                                                   float* __restrict__ out) {
    const int g = blockIdx.x;                      // 0..250
    const int b = blockIdx.y;

    #pragma unroll
    for (int e = 0; e < 6; ++e) {                  // 1536 = 6*256
        int i = threadIdx.x + 256 * e;
        int n = 2048 * g + i;
        int m = n - 1024;
        if (m < 0 || m >= OUT_LEN) continue;
        float s = 0.f;
        if (g > 0)
            s += scratch[(((size_t)b * BPB + (g - 1)) * 2 + 1) * 1536 + i];
        if (g < BPB)
            s += scratch[(((size_t)b * BPB + g) * 2) * 1536 + i];
        float r;
        if (n >= 1536 && n < 512000) {
            r = s * (2.f / 3.f);
        } else {
            int thi = n >> 9; if (thi > T_FRAMES - 1) thi = T_FRAMES - 1;
            int tlo = (n - (N_FFT - HOP)) >> 9; if (tlo < 0) tlo = 0;
            float wss = 0.f;
            for (int t = tlo; t <= thi; ++t) {
                float w = win[n - (t << 9)];
                wss += w * w;
            }
            r = (wss > 1.17549435e-38f) ? s / wss : s;
        }
        out[(size_t)b * OUT_LEN + m] = r;
    }
}

extern "C" void kernel_launch(void* const* d_in, const int* in_sizes, int n_in,
                              void* d_out, int out_size, void* d_ws, size_t ws_size,
                              hipStream_t stream) {
    const float* re  = (const float*)d_in[0];
    const float* im  = (const float*)d_in[1];
    // d_in[2], d_in[3] (W_real, W_imag) unused: the FFT computes their action.
    const float* win = (const float*)d_in[4];
    float* out = (float*)d_out;

    float* scratch = (float*)d_ws;   // 8 * 250 * 2 * 1536 * 4 B = 24,576,000 B

    istft_oa_kernel<<<dim3(BPB, 8), 256, 0, stream>>>(re, im, win, scratch, out);
    seam_kernel<<<dim3(BPB + 1, 8), 256, 0, stream>>>(scratch, win, out);
}

// Round 11
// 140.380 us; speedup vs baseline: 1.7866x; 1.0335x over previous
//
#include <hip/hip_runtime.h>

// ISTFT via batched real-IFFT (radix-4, in-place LDS) + in-LDS overlap-add.
//
// Identity: reference einsum with W_real/W_imag == win ⊙ IDFT_2048(hermitian
// extension); Im F[0], Im F[1024] multiply zero sin-columns (dropped).
// Per frame (n=2048, m=1024):
//   1) real-IFFT pack (k=0..1023), 1/m normalization folded in:
//      Z[k] = [ (X[k]+conj(X[m-k])) + i e^{+2πik/n}(X[k]-conj(X[m-k])) ]*0.5/m
//   2) 1024-pt complex inverse FFT: radix-4 DIT, digit-reversed input,
//      e^{+} twiddles; STAGE 0 FUSED INTO PACK (in registers); stages 1-3
//      in-place LDS (wave-local after stage 1); stage 4 fused with output.
//   3) x[2p]=Re z[p], x[2p+1]=Im z[p]; windowed samples accumulate into LDS OA.
//
// R19 vs R18 (counters: istft ~40 µs is LDS-PIPE-bound: ~196 KB LDS/frame =
// ~20 µs wire + 5.376M bank-conflict cycles ~9 µs; VALU only ~10 µs; more
// occupancy can't help a saturated LDS pipe):
//  - Stage 0 fused into pack: thread tid's four pack outputs k=tid+256q land
//    at digit-reversed indices 4m+q, m=digitrev4(tid) = exactly one stage-0
//    quad -> butterfly in registers, write results once. -8 LDS ops/thr/frame
//    (-17% traffic), one fewer round-trip.
//  - Stage 1 thread->butterfly map re-permuted (j=(tid>>4)&3,
//    g=(tid&15)|((tid>>6)<<4)): old map was a 4-way bank conflict (the only
//    conflicting pattern; all others audit 2-way/half = free); new map is
//    2-way/half = free. Wave-locality of stage-2/3 re-verified (wave w's
//    stage-1 writes cover [256w,256w+256) exactly, as before).
//  - Window float2 loads hoisted out of the d-loop.
//
// Structure: FPB=4, 2000 blocks; middle 512 outputs/block complete in-block
// (wss == 1.5 exact) -> stored directly; 1536-sample seams stored as fp32
// partials; seam_kernel sums trail(g-1)+lead(g) and normalizes.

#define N_FFT    2048
#define HOP      512
#define T_FRAMES 1000
#define F_BINS   1025
#define OUT_LEN  511488
#define FPB      4                         // frames per block
#define BPB      250                       // blocks per batch (250*4 = 1000)
#define OAF      3584                      // OA window floats: 4*512 + 1536

#define P(a) ((a) + ((a) >> 4))            // LDS pad (complex units)

__device__ __forceinline__ void cmul(float ar, float ai, float br, float bi,
                                     float& cr, float& ci) {
    cr = ar * br - ai * bi;
    ci = ar * bi + ai * br;
}

__global__ __launch_bounds__(256, 4) void istft_oa_kernel(const float* __restrict__ re,
                                                          const float* __restrict__ im,
                                                          const float* __restrict__ win,
                                                          float* __restrict__ scratch,
                                                          float* __restrict__ out) {
    __shared__ __align__(16) float2 buf[1088];     // P(1023)=1086
    __shared__ __align__(16) float2 oa2[OAF / 2];  // 1792 float2 = 3584 floats

    const int j   = blockIdx.x;            // block within batch
    const int b   = blockIdx.y;
    const int tid = threadIdx.x;
    const int t0  = j * FPB;

    // ---- zero the OA window (896 float4) ----
    {
        float4* z4 = (float4*)oa2;
        #pragma unroll
        for (int e = 0; e < 4; ++e) {
            int idx = tid + 256 * e;
            if (idx < 896) z4[idx] = make_float4(0.f, 0.f, 0.f, 0.f);
        }
    }

    // ---- hoisted constants (identical for all FPB frames) ----
    // m = digitrev4(tid): bit-reverse 8 bits, then swap adjacent bit pairs.
    const unsigned r8 = __brev((unsigned)tid) >> 24;
    const int m = (int)(((r8 & 0x55u) << 1) | ((r8 >> 1) & 0x55u));

    float pcs[4], psn[4];                  // pack: e^{i pi k/1024}, k = tid+256q
    #pragma unroll
    for (int q = 0; q < 4; ++q) {
        float ang = 3.14159265358979f * (float)(tid + 256 * q) / 1024.f;
        __sincosf(ang, &psn[q], &pcs[q]);
    }
    // stage-1 permuted mapping (bank-conflict-free): j1 in twiddle, g1 in base
    const int j1 = (tid >> 4) & 3;
    const int g1 = (tid & 15) | (((tid >> 6) & 3) << 4);
    float tc1[4], ts1[4], tc2[4], ts2[4], tc3[4], ts3[4];  // [0..2]=stages1..3, [3]=stage4
    #pragma unroll
    for (int s = 1; s < 4; ++s) {
        const int hm = 1 << (2 * s);
        const int jj = (s == 1) ? j1 : (tid & (hm - 1));
        float ang = 1.57079632679f * (float)jj / (float)hm;   // 2π j/(4hm)
        __sincosf(ang, &ts1[s - 1], &tc1[s - 1]);
        cmul(tc1[s-1], ts1[s-1], tc1[s-1], ts1[s-1], tc2[s-1], ts2[s-1]);
        cmul(tc2[s-1], ts2[s-1], tc1[s-1], ts1[s-1], tc3[s-1], ts3[s-1]);
    }
    {
        float ang = 1.57079632679f * (float)tid / 256.f;      // stage 4 (hm=256)
        __sincosf(ang, &ts1[3], &tc1[3]);
        cmul(tc1[3], ts1[3], tc1[3], ts1[3], tc2[3], ts2[3]);
        cmul(tc2[3], ts2[3], tc1[3], ts1[3], tc3[3], ts3[3]);
    }
    // window values used by stage-4 output (frame-independent)
    const float2* w2v = (const float2*)win;
    const float2 hw0 = w2v[tid],       hw1 = w2v[tid + 256];
    const float2 hw2 = w2v[tid + 512], hw3 = w2v[tid + 768];

    const float Sc = 0.5f / 1024.f;

    for (int d = 0; d < FPB; ++d) {
        const int f = b * T_FRAMES + t0 + d;
        const float* fr = re + (size_t)f * F_BINS;
        const float* fi = im + (size_t)f * F_BINS;

        // ---- pack to Z (registers) + stage-0 radix-4 (twiddle-free) ----
        float zr[4], zi[4];
        #pragma unroll
        for (int q = 0; q < 4; ++q) {
            int k = 256 * q + tid;
            float ar = fr[k];
            float ai = (k == 0) ? 0.f : fi[k];          // Im F[0] dropped
            int mk = 1024 - k;
            float br = fr[mk];
            float bi = (mk == 1024) ? 0.f : fi[mk];     // Im F[1024] dropped
            float dr = ar - br, di = ai + bi;           // X[k] - conj(X[m-k])
            float cs = pcs[q], sn = psn[q];
            zr[q] = (ar + br - (cs * di + sn * dr)) * Sc;
            zi[q] = (ai - bi + (cs * dr - sn * di)) * Sc;
        }
        {
            // quad m = digitrev4(tid); position c == q (verified: rk = 4m+q)
            float t0r = zr[0] + zr[2], t0i = zi[0] + zi[2];
            float t1r = zr[0] - zr[2], t1i = zi[0] - zi[2];
            float t2r = zr[1] + zr[3], t2i = zi[1] + zi[3];
            float t3r = zr[1] - zr[3], t3i = zi[1] - zi[3];
            buf[P(4 * m + 0)] = make_float2(t0r + t2r, t0i + t2i);
            buf[P(4 * m + 1)] = make_float2(t1r - t3i, t1i + t3r);   // + i*t3
            buf[P(4 * m + 2)] = make_float2(t0r - t2r, t0i - t2i);
            buf[P(4 * m + 3)] = make_float2(t1r + t3i, t1i - t3r);   // - i*t3
        }
        __syncthreads();   // stage-1 reads other threads' quads (cross-wave)

        // ---- stages 1..3: in-place LDS; stage1 cross-wave-safe (post-sync),
        //      stages 2-3 wave-local (wave w's s1 writes = [256w,256w+256)) ----
        #pragma unroll
        for (int s = 1; s < 4; ++s) {
            __builtin_amdgcn_wave_barrier();
            const int hm = 1 << (2 * s);
            int base;
            if (s == 1) {
                base = 16 * g1 + j1;                   // permuted, conflict-free
            } else {
                const int jj = tid & (hm - 1);
                base = ((tid - jj) << 2) + jj;
            }
            const float c1 = tc1[s-1], s1v = ts1[s-1];
            const float c2 = tc2[s-1], s2v = ts2[s-1];
            const float c3 = tc3[s-1], s3v = ts3[s-1];

            int i0 = P(base), i1 = P(base + hm), i2 = P(base + 2 * hm), i3 = P(base + 3 * hm);
            float2 a = buf[i0], bb = buf[i1], c = buf[i2], dd = buf[i3];
            float br_, bi_, cr_, ci_, dr_, di_;
            cmul(bb.x, bb.y, c1, s1v, br_, bi_);
            cmul(c.x,  c.y,  c2, s2v, cr_, ci_);
            cmul(dd.x, dd.y, c3, s3v, dr_, di_);

            float t0r = a.x + cr_, t0i = a.y + ci_;
            float t1r = a.x - cr_, t1i = a.y - ci_;
            float t2r = br_ + dr_, t2i = bi_ + di_;
            float t3r = br_ - dr_, t3i = bi_ - di_;
            buf[i0] = make_float2(t0r + t2r, t0i + t2i);
            buf[i1] = make_float2(t1r - t3i, t1i + t3r);
            buf[i2] = make_float2(t0r - t2r, t0i - t2i);
            buf[i3] = make_float2(t1r + t3i, t1i - t3r);
        }
        __syncthreads();   // stage 4 spans all 1024 points: cross-wave

        // ---- stage 4 (hm=256) fused with window + OA accumulate ----
        {
            const float c1 = tc1[3], s1v = ts1[3];
            const float c2 = tc2[3], s2v = ts2[3];
            const float c3 = tc3[3], s3v = ts3[3];

            int i0 = P(tid), i1 = P(tid + 256), i2 = P(tid + 512), i3 = P(tid + 768);
            float2 a = buf[i0], bb = buf[i1], c = buf[i2], dd = buf[i3];
            float br_, bi_, cr_, ci_, dr_, di_;
            cmul(bb.x, bb.y, c1, s1v, br_, bi_);
            cmul(c.x,  c.y,  c2, s2v, cr_, ci_);
            cmul(dd.x, dd.y, c3, s3v, dr_, di_);

            float t0r = a.x + cr_, t0i = a.y + ci_;
            float t1r = a.x - cr_, t1i = a.y - ci_;
            float t2r = br_ + dr_, t2i = bi_ + di_;
            float t3r = br_ - dr_, t3i = bi_ - di_;

            float2 z0 = make_float2(t0r + t2r, t0i + t2i);
            float2 z1 = make_float2(t1r - t3i, t1i + t3r);
            float2 z2 = make_float2(t0r - t2r, t0i - t2i);
            float2 z3 = make_float2(t1r + t3i, t1i - t3r);

            const int base2 = 256 * d;           // float2 index of 512*d
            float2 v;
            v = oa2[base2 + tid];
            v.x += z0.x * hw0.x;  v.y += z0.y * hw0.y;
            oa2[base2 + tid] = v;
            v = oa2[base2 + tid + 256];
            v.x += z1.x * hw1.x;  v.y += z1.y * hw1.y;
            oa2[base2 + tid + 256] = v;
            v = oa2[base2 + tid + 512];
            v.x += z2.x * hw2.x;  v.y += z2.y * hw2.y;
            oa2[base2 + tid + 512] = v;
            v = oa2[base2 + tid + 768];
            v.x += z3.x * hw3.x;  v.y += z3.y * hw3.y;
            oa2[base2 + tid + 768] = v;
        }
        __syncthreads();   // order OA adds vs next frame; buf free for next pack
    }

    // ---- complete region: floats [1536, 2048) -> out, wss == 1.5 exact ----
    const float inv = 2.f / 3.f;
    const float4* oa4 = (const float4*)oa2;
    if (tid < 128) {                              // 128 float4 = 512 floats
        float4 v = oa4[384 + tid];
        float4* o4 = (float4*)(out + (size_t)b * OUT_LEN + (size_t)2048 * j + 512);
        o4[tid] = make_float4(v.x * inv, v.y * inv, v.z * inv, v.w * inv);
    }
    // ---- seams: lead floats [0,1536), trail floats [2048,3584) -> scratch ----
    float4* sc4 = (float4*)(scratch + (((size_t)b * BPB + j) * 2) * 1536);
    #pragma unroll
    for (int e = 0; e < 3; ++e) {                 // 768 float4 exactly
        int idx = tid + 256 * e;
        float4 v = (idx < 384) ? oa4[idx] : oa4[idx + 128];  // trail f4 base = 512
        sc4[idx] = v;
    }
}

// Seam g of batch b covers n in [2048g, 2048g+1536); sum the trailing partial
// of block g-1 and the leading partial of block g. wss == 1.5 for
// n in [1536, 512000); generic gather wss at the global edges.
__global__ __launch_bounds__(256) void seam_kernel(const float* __restrict__ scratch,
                                                   const float* __restrict__ win,
                                                   float* __restrict__ out) {
    const int g = blockIdx.x;                      // 0..250
    const int b = blockIdx.y;

    #pragma unroll
    for (int e = 0; e < 6; ++e) {                  // 1536 = 6*256
        int i = threadIdx.x + 256 * e;
        int n = 2048 * g + i;
        int m = n - 1024;
        if (m < 0 || m >= OUT_LEN) continue;
        float s = 0.f;
        if (g > 0)
            s += scratch[(((size_t)b * BPB + (g - 1)) * 2 + 1) * 1536 + i];
        if (g < BPB)
            s += scratch[(((size_t)b * BPB + g) * 2) * 1536 + i];
        float r;
        if (n >= 1536 && n < 512000) {
            r = s * (2.f / 3.f);
        } else {
            int thi = n >> 9; if (thi > T_FRAMES - 1) thi = T_FRAMES - 1;
            int tlo = (n - (N_FFT - HOP)) >> 9; if (tlo < 0) tlo = 0;
            float wss = 0.f;
            for (int t = tlo; t <= thi; ++t) {
                float w = win[n - (t << 9)];
                wss += w * w;
            }
            r = (wss > 1.17549435e-38f) ? s / wss : s;
        }
        out[(size_t)b * OUT_LEN + m] = r;
    }
}

extern "C" void kernel_launch(void* const* d_in, const int* in_sizes, int n_in,
                              void* d_out, int out_size, void* d_ws, size_t ws_size,
                              hipStream_t stream) {
    const float* re  = (const float*)d_in[0];
    const float* im  = (const float*)d_in[1];
    // d_in[2], d_in[3] (W_real, W_imag) unused: the FFT computes their action.
    const float* win = (const float*)d_in[4];
    float* out = (float*)d_out;

    float* scratch = (float*)d_ws;   // 8 * 250 * 2 * 1536 * 4 B = 24,576,000 B

    istft_oa_kernel<<<dim3(BPB, 8), 256, 0, stream>>>(re, im, win, scratch, out);
    seam_kernel<<<dim3(BPB + 1, 8), 256, 0, stream>>>(scratch, win, out);
}

// Round 12
// 137.903 us; speedup vs baseline: 1.8186x; 1.0180x over previous
//
#include <hip/hip_runtime.h>

// ISTFT via batched real-IFFT (radix-4, in-place LDS) + REGISTER overlap-add.
//
// Identity: reference einsum with W_real/W_imag == win ⊙ IDFT_2048(hermitian
// extension); Im F[0], Im F[1024] multiply zero sin-columns (dropped).
// Per frame (n=2048, m=1024):
//   1) real-IFFT pack (k=0..1023), 1/m normalization folded in:
//      Z[k] = [ (X[k]+conj(X[m-k])) + i e^{+2πik/n}(X[k]-conj(X[m-k])) ]*0.5/m
//   2) 1024-pt complex inverse FFT: radix-4 DIT, digit-reversed input,
//      e^{+} twiddles; stage 0 fused into pack (registers); stages 1-3
//      in-place LDS; stage 4 fused with window + OA.
//   3) x[2p]=Re z[p], x[2p+1]=Im z[p]; windowed samples accumulate in REGISTERS.
//
// R20 vs R19 (istft ~33 µs, still LDS-wire-bound; OA r/w = 20% of LDS ops):
//  - OA buffer moved from LDS to registers. After stage 4, thread tid holds
//    z[tid+256r] (r=0..3); frame d's contribution goes to OA float2 slot
//    tid+256(d+r). Thread tid owns slots {tid+256m, m=0..6} as acc[7]
//    (d-loop fully unrolled -> static indices, no scratch). Deletes the
//    14 KB oa2 array, its zero-init, 8 LDS ops/thread/frame, and the final
//    re-read. LDS ops 40->32 per thread-frame; LDS 23.5 -> 8.7 KB.
//  - Final stores from acc: acc[3]*2/3 -> out direct region (m = 2048j+512+2tid,
//    float2, verified); acc[0..2] -> scratch lead float2 [tid+256m];
//    acc[4..6] -> scratch trail float2 [768+tid+256(m-4)] — float layout
//    identical to R19's, seam_kernel unchanged.
//
// Structure: FPB=4, 2000 blocks; middle 512 outputs/block complete in-block
// (wss == 1.5 exact) -> stored directly; 1536-sample seams stored as fp32
// partials; seam_kernel sums trail(g-1)+lead(g) and normalizes.

#define N_FFT    2048
#define HOP      512
#define T_FRAMES 1000
#define F_BINS   1025
#define OUT_LEN  511488
#define FPB      4                         // frames per block
#define BPB      250                       // blocks per batch (250*4 = 1000)

#define P(a) ((a) + ((a) >> 4))            // LDS pad (complex units)

__device__ __forceinline__ void cmul(float ar, float ai, float br, float bi,
                                     float& cr, float& ci) {
    cr = ar * br - ai * bi;
    ci = ar * bi + ai * br;
}

__global__ __launch_bounds__(256, 4) void istft_oa_kernel(const float* __restrict__ re,
                                                          const float* __restrict__ im,
                                                          const float* __restrict__ win,
                                                          float* __restrict__ scratch,
                                                          float* __restrict__ out) {
    __shared__ __align__(16) float2 buf[1088];     // P(1023)=1086; ONLY LDS use

    const int j   = blockIdx.x;            // block within batch
    const int b   = blockIdx.y;
    const int tid = threadIdx.x;
    const int t0  = j * FPB;

    // ---- hoisted constants (identical for all FPB frames) ----
    // m = digitrev4(tid): bit-reverse 8 bits, then swap adjacent bit pairs.
    const unsigned r8 = __brev((unsigned)tid) >> 24;
    const int mrev = (int)(((r8 & 0x55u) << 1) | ((r8 >> 1) & 0x55u));

    float pcs[4], psn[4];                  // pack: e^{i pi k/1024}, k = tid+256q
    #pragma unroll
    for (int q = 0; q < 4; ++q) {
        float ang = 3.14159265358979f * (float)(tid + 256 * q) / 1024.f;
        __sincosf(ang, &psn[q], &pcs[q]);
    }
    // stage-1 permuted mapping (bank-conflict-free): j1 in twiddle, g1 in base
    const int j1 = (tid >> 4) & 3;
    const int g1 = (tid & 15) | (((tid >> 6) & 3) << 4);
    float tc1[4], ts1[4], tc2[4], ts2[4], tc3[4], ts3[4];  // [0..2]=stages1..3, [3]=stage4
    #pragma unroll
    for (int s = 1; s < 4; ++s) {
        const int hm = 1 << (2 * s);
        const int jj = (s == 1) ? j1 : (tid & (hm - 1));
        float ang = 1.57079632679f * (float)jj / (float)hm;   // 2π j/(4hm)
        __sincosf(ang, &ts1[s - 1], &tc1[s - 1]);
        cmul(tc1[s-1], ts1[s-1], tc1[s-1], ts1[s-1], tc2[s-1], ts2[s-1]);
        cmul(tc2[s-1], ts2[s-1], tc1[s-1], ts1[s-1], tc3[s-1], ts3[s-1]);
    }
    {
        float ang = 1.57079632679f * (float)tid / 256.f;      // stage 4 (hm=256)
        __sincosf(ang, &ts1[3], &tc1[3]);
        cmul(tc1[3], ts1[3], tc1[3], ts1[3], tc2[3], ts2[3]);
        cmul(tc2[3], ts2[3], tc1[3], ts1[3], tc3[3], ts3[3]);
    }
    // window values used by stage-4 output (frame-independent)
    const float2* w2v = (const float2*)win;
    const float2 hw0 = w2v[tid],       hw1 = w2v[tid + 256];
    const float2 hw2 = w2v[tid + 512], hw3 = w2v[tid + 768];

    const float Sc = 0.5f / 1024.f;

    // ---- register OA: thread tid owns OA float2 slots {tid+256m, m=0..6} ----
    float2 acc0 = make_float2(0.f, 0.f), acc1 = make_float2(0.f, 0.f),
           acc2 = make_float2(0.f, 0.f), acc3 = make_float2(0.f, 0.f),
           acc4 = make_float2(0.f, 0.f), acc5 = make_float2(0.f, 0.f),
           acc6 = make_float2(0.f, 0.f);

    #pragma unroll
    for (int d = 0; d < FPB; ++d) {
        const int f = b * T_FRAMES + t0 + d;
        const float* fr = re + (size_t)f * F_BINS;
        const float* fi = im + (size_t)f * F_BINS;

        // ---- pack to Z (registers) + stage-0 radix-4 (twiddle-free) ----
        float zr[4], zi[4];
        #pragma unroll
        for (int q = 0; q < 4; ++q) {
            int k = 256 * q + tid;
            float ar = fr[k];
            float ai = (k == 0) ? 0.f : fi[k];          // Im F[0] dropped
            int mk = 1024 - k;
            float br = fr[mk];
            float bi = (mk == 1024) ? 0.f : fi[mk];     // Im F[1024] dropped
            float dr = ar - br, di = ai + bi;           // X[k] - conj(X[m-k])
            float cs = pcs[q], sn = psn[q];
            zr[q] = (ar + br - (cs * di + sn * dr)) * Sc;
            zi[q] = (ai - bi + (cs * dr - sn * di)) * Sc;
        }
        {
            // quad mrev = digitrev4(tid); position c == q (rk = 4*mrev+q)
            float t0r = zr[0] + zr[2], t0i = zi[0] + zi[2];
            float t1r = zr[0] - zr[2], t1i = zi[0] - zi[2];
            float t2r = zr[1] + zr[3], t2i = zi[1] + zi[3];
            float t3r = zr[1] - zr[3], t3i = zi[1] - zi[3];
            buf[P(4 * mrev + 0)] = make_float2(t0r + t2r, t0i + t2i);
            buf[P(4 * mrev + 1)] = make_float2(t1r - t3i, t1i + t3r);   // + i*t3
            buf[P(4 * mrev + 2)] = make_float2(t0r - t2r, t0i - t2i);
            buf[P(4 * mrev + 3)] = make_float2(t1r + t3i, t1i - t3r);   // - i*t3
        }
        __syncthreads();   // stage-1 reads other threads' quads (cross-wave)

        // ---- stages 1..3: in-place LDS; stage1 cross-wave-safe (post-sync),
        //      stages 2-3 wave-local (wave w's s1 writes = [256w,256w+256)) ----
        #pragma unroll
        for (int s = 1; s < 4; ++s) {
            __builtin_amdgcn_wave_barrier();
            const int hm = 1 << (2 * s);
            int base;
            if (s == 1) {
                base = 16 * g1 + j1;                   // permuted, conflict-free
            } else {
                const int jj = tid & (hm - 1);
                base = ((tid - jj) << 2) + jj;
            }
            const float c1 = tc1[s-1], s1v = ts1[s-1];
            const float c2 = tc2[s-1], s2v = ts2[s-1];
            const float c3 = tc3[s-1], s3v = ts3[s-1];

            int i0 = P(base), i1 = P(base + hm), i2 = P(base + 2 * hm), i3 = P(base + 3 * hm);
            float2 a = buf[i0], bb = buf[i1], c = buf[i2], dd = buf[i3];
            float br_, bi_, cr_, ci_, dr_, di_;
            cmul(bb.x, bb.y, c1, s1v, br_, bi_);
            cmul(c.x,  c.y,  c2, s2v, cr_, ci_);
            cmul(dd.x, dd.y, c3, s3v, dr_, di_);

            float t0r = a.x + cr_, t0i = a.y + ci_;
            float t1r = a.x - cr_, t1i = a.y - ci_;
            float t2r = br_ + dr_, t2i = bi_ + di_;
            float t3r = br_ - dr_, t3i = bi_ - di_;
            buf[i0] = make_float2(t0r + t2r, t0i + t2i);
            buf[i1] = make_float2(t1r - t3i, t1i + t3r);
            buf[i2] = make_float2(t0r - t2r, t0i - t2i);
            buf[i3] = make_float2(t1r + t3i, t1i - t3r);
        }
        __syncthreads();   // stage 4 spans all 1024 points: cross-wave

        // ---- stage 4 (hm=256) fused with window + register OA ----
        {
            const float c1 = tc1[3], s1v = ts1[3];
            const float c2 = tc2[3], s2v = ts2[3];
            const float c3 = tc3[3], s3v = ts3[3];

            int i0 = P(tid), i1 = P(tid + 256), i2 = P(tid + 512), i3 = P(tid + 768);
            float2 a = buf[i0], bb = buf[i1], c = buf[i2], dd = buf[i3];
            float br_, bi_, cr_, ci_, dr_, di_;
            cmul(bb.x, bb.y, c1, s1v, br_, bi_);
            cmul(c.x,  c.y,  c2, s2v, cr_, ci_);
            cmul(dd.x, dd.y, c3, s3v, dr_, di_);

            float t0r = a.x + cr_, t0i = a.y + ci_;
            float t1r = a.x - cr_, t1i = a.y - ci_;
            float t2r = br_ + dr_, t2i = bi_ + di_;
            float t3r = br_ - dr_, t3i = bi_ - di_;

            // z_r = z[tid+256r]; frame d: acc[d+r] += z_r .* hw_r  (static idx)
            float2 z0 = make_float2((t0r + t2r) * hw0.x, (t0i + t2i) * hw0.y);
            float2 z1 = make_float2((t1r - t3i) * hw1.x, (t1i + t3r) * hw1.y);
            float2 z2 = make_float2((t0r - t2r) * hw2.x, (t0i - t2i) * hw2.y);
            float2 z3 = make_float2((t1r + t3i) * hw3.x, (t1i - t3r) * hw3.y);

            if (d == 0) {
                acc0.x += z0.x; acc0.y += z0.y;  acc1.x += z1.x; acc1.y += z1.y;
                acc2.x += z2.x; acc2.y += z2.y;  acc3.x += z3.x; acc3.y += z3.y;
            } else if (d == 1) {
                acc1.x += z0.x; acc1.y += z0.y;  acc2.x += z1.x; acc2.y += z1.y;
                acc3.x += z2.x; acc3.y += z2.y;  acc4.x += z3.x; acc4.y += z3.y;
            } else if (d == 2) {
                acc2.x += z0.x; acc2.y += z0.y;  acc3.x += z1.x; acc3.y += z1.y;
                acc4.x += z2.x; acc4.y += z2.y;  acc5.x += z3.x; acc5.y += z3.y;
            } else {
                acc3.x += z0.x; acc3.y += z0.y;  acc4.x += z1.x; acc4.y += z1.y;
                acc5.x += z2.x; acc5.y += z2.y;  acc6.x += z3.x; acc6.y += z3.y;
            }
        }
        __syncthreads();   // buf free for next frame's pack scatter
    }

    // ---- direct region: acc3 = OA float2 slot tid+768 (floats 1536+2tid),
    //      out float m = 2048j + 512 + 2tid, wss == 1.5 exact ----
    const float inv = 2.f / 3.f;
    {
        float2* o2 = (float2*)(out + (size_t)b * OUT_LEN + (size_t)2048 * j + 512);
        o2[tid] = make_float2(acc3.x * inv, acc3.y * inv);
    }
    // ---- seams: lead = acc0..2 (floats [0,1536)), trail = acc4..6
    //      (floats [2048,3584)); float layout identical to R19 ----
    float2* sc2 = (float2*)(scratch + (((size_t)b * BPB + j) * 2) * 1536);
    sc2[tid]        = acc0;
    sc2[tid + 256]  = acc1;
    sc2[tid + 512]  = acc2;
    sc2[tid + 768]  = acc4;
    sc2[tid + 1024] = acc5;
    sc2[tid + 1280] = acc6;
}

// Seam g of batch b covers n in [2048g, 2048g+1536); sum the trailing partial
// of block g-1 and the leading partial of block g. wss == 1.5 for
// n in [1536, 512000); generic gather wss at the global edges.
__global__ __launch_bounds__(256) void seam_kernel(const float* __restrict__ scratch,
                                                   const float* __restrict__ win,
                                                   float* __restrict__ out) {
    const int g = blockIdx.x;                      // 0..250
    const int b = blockIdx.y;

    #pragma unroll
    for (int e = 0; e < 6; ++e) {                  // 1536 = 6*256
        int i = threadIdx.x + 256 * e;
        int n = 2048 * g + i;
        int m = n - 1024;
        if (m < 0 || m >= OUT_LEN) continue;
        float s = 0.f;
        if (g > 0)
            s += scratch[(((size_t)b * BPB + (g - 1)) * 2 + 1) * 1536 + i];
        if (g < BPB)
            s += scratch[(((size_t)b * BPB + g) * 2) * 1536 + i];
        float r;
        if (n >= 1536 && n < 512000) {
            r = s * (2.f / 3.f);
        } else {
            int thi = n >> 9; if (thi > T_FRAMES - 1) thi = T_FRAMES - 1;
            int tlo = (n - (N_FFT - HOP)) >> 9; if (tlo < 0) tlo = 0;
            float wss = 0.f;
            for (int t = tlo; t <= thi; ++t) {
                float w = win[n - (t << 9)];
                wss += w * w;
            }
            r = (wss > 1.17549435e-38f) ? s / wss : s;
        }
        out[(size_t)b * OUT_LEN + m] = r;
    }
}

extern "C" void kernel_launch(void* const* d_in, const int* in_sizes, int n_in,
                              void* d_out, int out_size, void* d_ws, size_t ws_size,
                              hipStream_t stream) {
    const float* re  = (const float*)d_in[0];
    const float* im  = (const float*)d_in[1];
    // d_in[2], d_in[3] (W_real, W_imag) unused: the FFT computes their action.
    const float* win = (const float*)d_in[4];
    float* out = (float*)d_out;

    float* scratch = (float*)d_ws;   // 8 * 250 * 2 * 1536 * 4 B = 24,576,000 B

    istft_oa_kernel<<<dim3(BPB, 8), 256, 0, stream>>>(re, im, win, scratch, out);
    seam_kernel<<<dim3(BPB + 1, 8), 256, 0, stream>>>(scratch, win, out);
}